// Round 1
// baseline (554.435 us; speedup 1.0000x reference)
//
#include <hip/hip_runtime.h>
#include <hip/hip_bf16.h>
#include <math.h>

#define NH 8
#define L 512
#define DP 128
#define DS 16
#define DCAT 1280
#define TJ 32            // j-rows of e per tile
#define NCHUNK 4         // blocks per (b,i) row
#define CJ 128           // j-rows per chunk (L / NCHUNK)
#define PSTRIDE 1280     // floats per partial row

#define SCALE_SCALAR 0.25f
#define SCALE_POINT  0.23570226039551584f   // (4.5*4)^-0.5
#define SCALE_TOTAL  0.5773502691896258f    // 3^-0.5

typedef __bf16 bf16_t;
typedef bf16_t bf16x8 __attribute__((ext_vector_type(8)));
typedef float  f32x4v __attribute__((ext_vector_type(4)));

// ---------------------------------------------------------------------------
// k_pack: x -> bf16 (row-major 1024x384), all six W -> WallT (672x384 bf16)
// ---------------------------------------------------------------------------
__global__ __launch_bounds__(256) void k_pack(
    const float* __restrict__ x,
    const float* __restrict__ Wq_s, const float* __restrict__ Wk_s, const float* __restrict__ Wv_s,
    const float* __restrict__ Wq_p, const float* __restrict__ Wk_p, const float* __restrict__ Wv_p,
    __hip_bfloat16* __restrict__ xb, __hip_bfloat16* __restrict__ WallT) {
    int idx = blockIdx.x * 256 + threadIdx.x;          // 651264 total
    const int T1 = 1024 * 384;
    if (idx < T1) {
        xb[idx] = __float2bfloat16(x[idx]);
    } else {
        int j = idx - T1;                              // 0 .. 258047
        int n = j / 384, k = j % 384;
        float v;
        if      (n < 128) v = Wq_s[k * 128 + n];
        else if (n < 256) v = Wk_s[k * 128 + (n - 128)];
        else if (n < 384) v = Wv_s[k * 128 + (n - 256)];
        else if (n < 480) v = Wq_p[k * 96  + (n - 384)];
        else if (n < 576) v = Wk_p[k * 96  + (n - 480)];
        else              v = Wv_p[k * 96  + (n - 576)];
        WallT[(size_t)n * 384 + k] = __float2bfloat16(v);
    }
}

// ---------------------------------------------------------------------------
// k_prep: Wout (1280,384) fp32 -> WoutT (384,1280) bf16, tiled LDS transpose
// ---------------------------------------------------------------------------
__global__ __launch_bounds__(256) void k_prep(const float* __restrict__ Wout,
                                              __hip_bfloat16* __restrict__ WoutT) {
    __shared__ float tile[64][65];
    const int tid = threadIdx.x;
    const int k0 = blockIdx.x * 64;   // 20 blocks
    const int n0 = blockIdx.y * 64;   // 6 blocks
#pragma unroll
    for (int s = 0; s < 16; ++s) {
        int idx = s * 256 + tid, kk = idx >> 6, nn = idx & 63;
        tile[kk][nn] = Wout[(size_t)(k0 + kk) * 384 + n0 + nn];
    }
    __syncthreads();
#pragma unroll
    for (int s = 0; s < 16; ++s) {
        int idx = s * 256 + tid, nn = idx >> 6, kk = idx & 63;
        WoutT[(size_t)(n0 + nn) * 1280 + k0 + kk] = __float2bfloat16(tile[kk][nn]);
    }
}

// ---------------------------------------------------------------------------
// k_projm: [1024,672] = xb[1024,384] @ Wall[384,672]  (bf16 MFMA, fp32 out)
// ---------------------------------------------------------------------------
__global__ __launch_bounds__(256) void k_projm(
    const __hip_bfloat16* __restrict__ xb, const __hip_bfloat16* __restrict__ WallT,
    float* __restrict__ q_s, float* __restrict__ k_s, float* __restrict__ v_s,
    float* __restrict__ praw) {
    __shared__ __align__(16) bf16_t As[64 * 40];
    __shared__ __align__(16) bf16_t Bs[48 * 40];
    const int tid = threadIdx.x;
    const int row0 = blockIdx.x * 64, col0 = blockIdx.y * 48;
    const int w = tid >> 6, lane = tid & 63;
    f32x4v acc[3] = {};

    for (int k0 = 0; k0 < 384; k0 += 32) {
        __syncthreads();
        {
            int rr = tid >> 2, q = tid & 3;
            *reinterpret_cast<int4*>(&As[rr * 40 + q * 8]) =
                *reinterpret_cast<const int4*>(&xb[(size_t)(row0 + rr) * 384 + k0 + q * 8]);
            if (tid < 192)
                *reinterpret_cast<int4*>(&Bs[rr * 40 + q * 8]) =
                    *reinterpret_cast<const int4*>(&WallT[(size_t)(col0 + rr) * 384 + k0 + q * 8]);
        }
        __syncthreads();
        const int m = lane & 15, kq = lane >> 4;
        bf16x8 af = *reinterpret_cast<const bf16x8*>(&As[(w * 16 + m) * 40 + kq * 8]);
#pragma unroll
        for (int c = 0; c < 3; ++c) {
            bf16x8 bfr = *reinterpret_cast<const bf16x8*>(&Bs[(c * 16 + m) * 40 + kq * 8]);
            acc[c] = __builtin_amdgcn_mfma_f32_16x16x32_bf16(af, bfr, acc[c], 0, 0, 0);
        }
    }
    const int colL = lane & 15, rbase = (lane >> 4) * 4;
#pragma unroll
    for (int c = 0; c < 3; ++c) {
        int col = col0 + c * 16 + colL;
#pragma unroll
        for (int rg = 0; rg < 4; ++rg) {
            int row = row0 + w * 16 + rbase + rg;
            float v = acc[c][rg];
            int bb = row >> 9, ll = row & 511;
            if (col < 384) {
                int kind = col >> 7, n = (col >> 4) & 7, d = col & 15;
                float* dst = (kind == 0) ? q_s : (kind == 1) ? k_s : v_s;
                dst[((size_t)(bb * NH + n) * L + ll) * DS + d] = v;
            } else {
                praw[(size_t)row * 288 + (col - 384)] = v;
            }
        }
    }
}

// ---------------------------------------------------------------------------
// k_euclid: praw (1024x288) -> q_p/k_p/v_p with forward euclid  x@r + t
// ---------------------------------------------------------------------------
__global__ __launch_bounds__(256) void k_euclid(
    const float* __restrict__ praw, const float* __restrict__ r, const float* __restrict__ t,
    float* __restrict__ q_p, float* __restrict__ k_p, float* __restrict__ v_p) {
    int idx = blockIdx.x * 256 + threadIdx.x;          // 294912 total
    int row = idx / 288, o = idx % 288;
    int arr = o / 96, oo = o % 96;
    int n = oo / 12, pc = oo % 12, p = pc / 3, c = pc % 3;
    const float* base = praw + (size_t)row * 288 + arr * 96 + n * 12 + p * 3;
    float acc = t[row * 3 + c];
#pragma unroll
    for (int k = 0; k < 3; ++k) acc += base[k] * r[row * 9 + k * 3 + c];
    float* dst = (arr == 0) ? q_p : (arr == 1) ? k_p : v_p;
    int bb = row >> 9, ll = row & 511;
    dst[((size_t)(bb * NH + n) * L + ll) * 12 + pc] = acc;
}

// ---------------------------------------------------------------------------
// k_attn v2: per (b,i,chunk) block.
//  - e tile double-buffered in LDS via global_load_lds (async prefetch, the
//    next tile's loads are in flight across one full compute phase).
//  - bias e@Wpb computed k-split: thread (kq,jL) covers 16 k-values for ALL
//    8 heads -> each e element read from LDS exactly once (was 8x), Wpb rows
//    are wave-broadcast reads; partials reduced through small swizzled ps[].
//  - f32x4 ext-vector accumulators for bias + out_pair -> v_pk_fma_f32.
// Numerics: fp32 reassociation of the 128-dot only (k summed in 16-chunks).
// ---------------------------------------------------------------------------
__global__ __launch_bounds__(256) void k_attn(
    const float* __restrict__ e, const float* __restrict__ Wpb, const float* __restrict__ gamma,
    const float* __restrict__ q_s, const float* __restrict__ k_s, const float* __restrict__ v_s,
    const float* __restrict__ q_p, const float* __restrict__ k_p, const float* __restrict__ v_p,
    float* __restrict__ part) {
    __shared__ __align__(16) float et[2][TJ * DP];  // 32 KB, float4-xor-swizzled, dbuf
    __shared__ __align__(16) float wpbK[DP * NH];   // Wpb row-major [k][n], 4 KB
    __shared__ float ps[8 * TJ * NH];               // bias partials [kq][jL][n^(jL&7)], 8 KB
    __shared__ float pt[NH][36];                    // [n][j] (+pad)
    __shared__ float ptT[TJ][NH];                   // [j][n]
    __shared__ __align__(16) float qsl[NH * 16];
    __shared__ __align__(16) float qpl[NH * 12];
    __shared__ float gsh[NH];

    const int tid = threadIdx.x;
    const int blk = blockIdx.x;
    const int bi = blk >> 2, chunk = blk & 3;
    const int b = bi >> 9, i = bi & 511, b8 = b * NH;
    const int nH = tid >> 5, jL = tid & 31;         // role1: kq=nH k-slice; role2: head nH
    const int d4 = tid & 31, jsub = tid >> 5;       // out_pair: float4 group, j-subgroup

    // ---- prologue loads ----
    reinterpret_cast<float4*>(wpbK)[tid] = reinterpret_cast<const float4*>(Wpb)[tid];
    if (tid < 128) {
        int n = tid >> 4, d = tid & 15;
        qsl[n * 16 + d] = q_s[((size_t)(b8 + n) * L + i) * DS + d];
    } else if (tid < 224) {
        int o = tid - 128, n = o / 12, pc = o % 12;
        qpl[n * 12 + pc] = q_p[((size_t)(b8 + n) * L + i) * 12 + pc];
    } else if (tid < 232) {
        gsh[tid - 224] = gamma[tid - 224];
    }

    // sv ownership (phase C)
    const int nS = tid >> 4, dS = tid & 15;                      // tid < 128
    const int oP = tid - 128;
    const int nP = (oP >= 0 && oP < 96) ? oP / 12 : 0;
    const int pcP = (oP >= 0 && oP < 96) ? oP % 12 : 0;
    const float* vsp = v_s + (((size_t)(b8 + nS) * L + chunk * CJ) << 4) + dS;
    const float* vpp = v_p + ((size_t)(b8 + nP) * L + chunk * CJ) * 12 + pcP;

    const float4* esrc4 = reinterpret_cast<const float4*>(
        e + ((size_t)(b * L + i) * L + chunk * CJ) * DP);

    // async stage of one 32-row e tile into et[buf]; dest linear, source
    // pre-xor-swizzled so readers use et4[j*32 + (g^j)]  (G21: both-sides)
    const int wbase = tid & 192;   // wave base (wv*64)
    auto stage = [&](int buf, int j0) {
        float* etb = &et[buf][0];
#pragma unroll
        for (int s = 0; s < 4; ++s) {
            int idx = s * 256 + tid;
            int j = idx >> 5, g = (idx & 31) ^ j;
            const float* src = reinterpret_cast<const float*>(esrc4 + (size_t)(j0 + j) * 32 + g);
            __builtin_amdgcn_global_load_lds(
                (const __attribute__((address_space(1))) void*)src,
                (__attribute__((address_space(3))) void*)(etb + (size_t)(s * 256 + wbase) * 4),
                16, 0, 0);
        }
    };

    float lsum = 0.f;
    f32x4v accPair[NH] = {};
    float accS = 0.f, accP = 0.f;

    stage(0, 0);
    __syncthreads();     // tile0 + prologue LDS visible

    int cur = 0;
    for (int tile = 0; tile < CJ / TJ; ++tile) {
        const int j0 = tile * TJ;
        if (tile < CJ / TJ - 1) stage(cur ^ 1, j0 + TJ);   // prefetch next tile

        const f32x4v* e4 = reinterpret_cast<const f32x4v*>(&et[cur][0]);

        // ---- phase A: bias partials (kq-split) + ssum/sq (global) ----
        f32x4v a0 = {}, a1 = {};
        {
            const f32x4v* wp4 = reinterpret_cast<const f32x4v*>(wpbK);
#pragma unroll
            for (int f = 0; f < 4; ++f) {
                f32x4v ev = e4[jL * 32 + ((nH * 4 + f) ^ jL)];
                const f32x4v* wk = wp4 + (size_t)(nH * 16 + f * 4) * 2;
                a0 += ev.x * wk[0]; a1 += ev.x * wk[1];
                a0 += ev.y * wk[2]; a1 += ev.y * wk[3];
                a0 += ev.z * wk[4]; a1 += ev.z * wk[5];
                a0 += ev.w * wk[6]; a1 += ev.w * wk[7];
            }
        }
        const int jg = chunk * CJ + j0 + jL;
        float ssum = 0.f, sq = 0.f;
        {
            const float4* ksr = reinterpret_cast<const float4*>(k_s + (((size_t)(b8 + nH) * L + jg) << 4));
            const float4* q4 = reinterpret_cast<const float4*>(&qsl[nH * 16]);
#pragma unroll
            for (int g = 0; g < 4; ++g) {
                float4 kv = ksr[g], qv = q4[g];
                ssum += kv.x * qv.x + kv.y * qv.y + kv.z * qv.z + kv.w * qv.w;
            }
            const float4* kpr = reinterpret_cast<const float4*>(k_p + ((size_t)(b8 + nH) * L + jg) * 12);
            const float4* qp4 = reinterpret_cast<const float4*>(&qpl[nH * 12]);
#pragma unroll
            for (int g = 0; g < 3; ++g) {
                float4 kv = kpr[g], qv = qp4[g];
                float d0;
                d0 = qv.x - kv.x; sq += d0 * d0;  d0 = qv.y - kv.y; sq += d0 * d0;
                d0 = qv.z - kv.z; sq += d0 * d0;  d0 = qv.w - kv.w; sq += d0 * d0;
            }
        }
        {   // store partials, head-slot xor'd by jL&7 to spread banks
            int pb = (nH * TJ + jL) * NH, sw = jL & 7;
            ps[pb + (0 ^ sw)] = a0.x; ps[pb + (1 ^ sw)] = a0.y;
            ps[pb + (2 ^ sw)] = a0.z; ps[pb + (3 ^ sw)] = a0.w;
            ps[pb + (4 ^ sw)] = a1.x; ps[pb + (5 ^ sw)] = a1.y;
            ps[pb + (6 ^ sw)] = a1.z; ps[pb + (7 ^ sw)] = a1.w;
        }
        __syncthreads();    // ps visible (also drains prefetch vmcnt)

        // ---- phase B: combine partials, logit, exp ----
        {
            float bsum = 0.f;
            const int sw = nH ^ (jL & 7);
#pragma unroll
            for (int kq = 0; kq < 8; ++kq) bsum += ps[(kq * TJ + jL) * NH + sw];
            float lg = SCALE_TOTAL * (ssum * SCALE_SCALAR + bsum
                                      - 0.5f * SCALE_POINT * gsh[nH] * sq);
            float pv = __expf(lg);
            lsum += pv;
            pt[nH][jL] = pv;
            ptT[jL][nH] = pv;
        }
        __syncthreads();    // pt/ptT visible

        // ---- phase C: out_pair (4 j-rows/thread), out_scalar, out_point ----
        {
#pragma unroll
            for (int s = 0; s < 4; ++s) {
                int j = jsub * 4 + s;
                f32x4v ev = e4[j * 32 + (d4 ^ j)];
                const float4* pb4 = reinterpret_cast<const float4*>(&ptT[j][0]);
                float4 pA = pb4[0], pB = pb4[1];
                accPair[0] += pA.x * ev; accPair[1] += pA.y * ev;
                accPair[2] += pA.z * ev; accPair[3] += pA.w * ev;
                accPair[4] += pB.x * ev; accPair[5] += pB.y * ev;
                accPair[6] += pB.z * ev; accPair[7] += pB.w * ev;
            }
        }
        if (tid < 128) {
            const float* vp = vsp + (size_t)j0 * 16;
#pragma unroll
            for (int q = 0; q < 8; ++q) {
                float4 p4 = *reinterpret_cast<const float4*>(&pt[nS][q * 4]);
                accS += p4.x * vp[(q * 4 + 0) * 16] + p4.y * vp[(q * 4 + 1) * 16]
                      + p4.z * vp[(q * 4 + 2) * 16] + p4.w * vp[(q * 4 + 3) * 16];
            }
        } else if (tid < 224) {
            const float* vp = vpp + (size_t)j0 * 12;
#pragma unroll
            for (int q = 0; q < 8; ++q) {
                float4 p4 = *reinterpret_cast<const float4*>(&pt[nP][q * 4]);
                accP += p4.x * vp[(q * 4 + 0) * 12] + p4.y * vp[(q * 4 + 1) * 12]
                      + p4.z * vp[(q * 4 + 2) * 12] + p4.w * vp[(q * 4 + 3) * 12];
            }
        }
        __syncthreads();    // et[cur] consumed -> safe to restage next iter
        cur ^= 1;
    }

    // ---- write partials ----
    float* prow = part + (size_t)blk * PSTRIDE;
    lsum += __shfl_xor(lsum, 1);  lsum += __shfl_xor(lsum, 2);
    lsum += __shfl_xor(lsum, 4);  lsum += __shfl_xor(lsum, 8);
    lsum += __shfl_xor(lsum, 16);
    if (jL == 0) prow[1248 + nH] = lsum;
    if (tid < 128) prow[1024 + tid] = accS;
    else if (tid < 224) prow[1152 + (tid - 128)] = accP;

    // pair reduction over 8 jsub groups (log rounds through et[0])
    f32x4v* red4 = reinterpret_cast<f32x4v*>(&et[0][0]);
    __syncthreads();
    if (jsub >= 4) {
#pragma unroll
        for (int n = 0; n < NH; ++n) red4[((jsub - 4) * NH + n) * 32 + d4] = accPair[n];
    }
    __syncthreads();
    if (jsub < 4) {
#pragma unroll
        for (int n = 0; n < NH; ++n) accPair[n] += red4[(jsub * NH + n) * 32 + d4];
    }
    __syncthreads();
    if (jsub == 2 || jsub == 3) {
#pragma unroll
        for (int n = 0; n < NH; ++n) red4[((jsub - 2) * NH + n) * 32 + d4] = accPair[n];
    }
    __syncthreads();
    if (jsub < 2) {
#pragma unroll
        for (int n = 0; n < NH; ++n) accPair[n] += red4[(jsub * NH + n) * 32 + d4];
    }
    __syncthreads();
    if (jsub == 1) {
#pragma unroll
        for (int n = 0; n < NH; ++n) red4[n * 32 + d4] = accPair[n];
    }
    __syncthreads();
    if (jsub == 0) {
#pragma unroll
        for (int n = 0; n < NH; ++n) {
            accPair[n] += red4[n * 32 + d4];
            *reinterpret_cast<f32x4v*>(&prow[n * 128 + d4 * 4]) = accPair[n];
        }
    }
}

// ---------------------------------------------------------------------------
// k_comb: combine 4 chunk-partials per (b,i); normalize; epilogue; write concat
// ---------------------------------------------------------------------------
__global__ __launch_bounds__(256) void k_comb(
    const float* __restrict__ part, const float* __restrict__ r, const float* __restrict__ t,
    __hip_bfloat16* __restrict__ concat) {
    __shared__ float comb[1256];
    __shared__ float rtsh[12], osh[96], o2sh[96];
    const int tid = threadIdx.x;
    const int bi = blockIdx.x;
    const float* base = part + (size_t)bi * NCHUNK * PSTRIDE;
#pragma unroll
    for (int s = 0; s < 5; ++s) {
        int idx = tid + s * 256;
        if (idx < 1256)
            comb[idx] = base[idx] + base[PSTRIDE + idx] + base[2 * PSTRIDE + idx] + base[3 * PSTRIDE + idx];
    }
    if (tid >= 244 && tid < 256) {
        int c = tid - 244;
        rtsh[c] = (c < 9) ? r[bi * 9 + c] : t[bi * 3 + (c - 9)];
    }
    __syncthreads();
    __hip_bfloat16* crow = concat + (size_t)bi * DCAT;
    if (tid < 128) crow[tid] = __float2bfloat16(comb[1024 + tid] / comb[1248 + (tid >> 4)]);
    for (int idx = tid; idx < 1024; idx += 256)
        crow[128 + idx] = __float2bfloat16(comb[idx] / comb[1248 + (idx >> 7)]);
    if (tid >= 128 && tid < 224) {
        int o = tid - 128;
        osh[o] = comb[1152 + o] / comb[1248 + o / 12];
    }
    __syncthreads();
    if (tid < 96) {   // inverse euclid: o_c = sum_k (op_k - t_k) * r[c][k]
        int n = tid / 12, pc = tid % 12, p = pc / 3, c = pc % 3;
        float oc = 0.f;
#pragma unroll
        for (int k = 0; k < 3; ++k)
            oc += (osh[n * 12 + p * 3 + k] - rtsh[9 + k]) * rtsh[c * 3 + k];
        crow[1152 + tid] = __float2bfloat16(oc);
        o2sh[tid] = oc;
    }
    __syncthreads();
    if (tid < 32) {
        int n = tid >> 2, p = tid & 3;
        float vx = o2sh[n * 12 + p * 3], vy = o2sh[n * 12 + p * 3 + 1], vz = o2sh[n * 12 + p * 3 + 2];
        crow[1248 + tid] = __float2bfloat16(sqrtf(vx * vx + vy * vy + vz * vz));
    }
}

// ---------------------------------------------------------------------------
// k_out: bf16 MFMA GEMM: out[1024,384] = concat[1024,1280] @ Wout + bout
// ---------------------------------------------------------------------------
__global__ __launch_bounds__(256) void k_out(const __hip_bfloat16* __restrict__ A,
                                             const __hip_bfloat16* __restrict__ Bt,
                                             const float* __restrict__ bout,
                                             float* __restrict__ out) {
    __shared__ __align__(16) bf16_t At[64 * 40];
    __shared__ __align__(16) bf16_t Bs[64 * 40];
    const int tid = threadIdx.x;
    const int row0 = blockIdx.x * 64, col0 = blockIdx.y * 64;
    const int wv = tid >> 6, lane = tid & 63;
    f32x4v acc[4] = {};

    for (int k0 = 0; k0 < 1280; k0 += 32) {
        __syncthreads();
        {
            int rr = tid >> 2, q = tid & 3;
            *reinterpret_cast<int4*>(&At[rr * 40 + q * 8]) =
                *reinterpret_cast<const int4*>(&A[(size_t)(row0 + rr) * 1280 + k0 + q * 8]);
            *reinterpret_cast<int4*>(&Bs[rr * 40 + q * 8]) =
                *reinterpret_cast<const int4*>(&Bt[(size_t)(col0 + rr) * 1280 + k0 + q * 8]);
        }
        __syncthreads();
        const int m = lane & 15, kq = lane >> 4;
        bf16x8 af = *reinterpret_cast<const bf16x8*>(&At[(wv * 16 + m) * 40 + kq * 8]);
#pragma unroll
        for (int nt = 0; nt < 4; ++nt) {
            bf16x8 bfr = *reinterpret_cast<const bf16x8*>(&Bs[(nt * 16 + m) * 40 + kq * 8]);
            acc[nt] = __builtin_amdgcn_mfma_f32_16x16x32_bf16(af, bfr, acc[nt], 0, 0, 0);
        }
    }
    const int col_l = lane & 15, rbase = (lane >> 4) * 4;
#pragma unroll
    for (int nt = 0; nt < 4; ++nt) {
        int col = col0 + nt * 16 + col_l;
        float bo = bout[col];
#pragma unroll
        for (int rg = 0; rg < 4; ++rg) {
            int rowg = row0 + wv * 16 + rbase + rg;
            out[(size_t)rowg * 384 + col] = acc[nt][rg] + bo;
        }
    }
}

// ---------------------------------------------------------------------------
extern "C" void kernel_launch(void* const* d_in, const int* in_sizes, int n_in,
                              void* d_out, int out_size, void* d_ws, size_t ws_size,
                              hipStream_t stream) {
    const float* x     = (const float*)d_in[0];
    const float* e     = (const float*)d_in[1];
    const float* r     = (const float*)d_in[2];
    const float* t     = (const float*)d_in[3];
    const float* Wq_s  = (const float*)d_in[4];
    const float* Wk_s  = (const float*)d_in[5];
    const float* Wv_s  = (const float*)d_in[6];
    const float* Wpb   = (const float*)d_in[7];
    const float* Wq_p  = (const float*)d_in[8];
    const float* Wk_p  = (const float*)d_in[9];
    const float* Wv_p  = (const float*)d_in[10];
    const float* gamma = (const float*)d_in[11];
    const float* Wout  = (const float*)d_in[12];
    const float* bout  = (const float*)d_in[13];

    float* ws   = (float*)d_ws;
    float* q_s  = ws + 0;          // 131072
    float* k_s  = ws + 131072;     // 131072
    float* v_s  = ws + 262144;     // 131072
    float* q_p  = ws + 393216;     // 98304
    float* k_p  = ws + 491520;     // 98304
    float* v_p  = ws + 589824;     // 98304
    float* praw = ws + 688128;     // 294912
    __hip_bfloat16* xb     = (__hip_bfloat16*)((char*)d_ws + 3932160); // 393216 bf16
    __hip_bfloat16* WallT  = (__hip_bfloat16*)((char*)d_ws + 4718592); // 258048 bf16
    __hip_bfloat16* concat = (__hip_bfloat16*)((char*)d_ws + 5234688); // 1310720 bf16
    __hip_bfloat16* WoutT  = (__hip_bfloat16*)((char*)d_ws + 7856128); // 491520 bf16
    float* part = (float*)((char*)d_ws + 8847360);                     // 4096*1280 fp32
    float* out = (float*)d_out;

    hipLaunchKernelGGL(k_pack, dim3(2544), dim3(256), 0, stream,
                       x, Wq_s, Wk_s, Wv_s, Wq_p, Wk_p, Wv_p, xb, WallT);
    hipLaunchKernelGGL(k_prep, dim3(20, 6), dim3(256), 0, stream, Wout, WoutT);
    hipLaunchKernelGGL(k_projm, dim3(16, 14), dim3(256), 0, stream,
                       xb, WallT, q_s, k_s, v_s, praw);
    hipLaunchKernelGGL(k_euclid, dim3(1152), dim3(256), 0, stream,
                       praw, r, t, q_p, k_p, v_p);
    hipLaunchKernelGGL(k_attn, dim3(4096), dim3(256), 0, stream,
                       e, Wpb, gamma, q_s, k_s, v_s, q_p, k_p, v_p, part);
    hipLaunchKernelGGL(k_comb, dim3(1024), dim3(256), 0, stream,
                       part, r, t, concat);
    hipLaunchKernelGGL(k_out, dim3(16, 6), dim3(256), 0, stream, concat, WoutT, bout, out);
}

// Round 3
// 479.829 us; speedup vs baseline: 1.1555x; 1.1555x over previous
//
#include <hip/hip_runtime.h>
#include <hip/hip_bf16.h>
#include <math.h>

#define NH 8
#define L 512
#define DP 128
#define DS 16
#define DCAT 1280
#define TJ 32            // j-rows of e per tile
#define NCHUNK 4         // blocks per (b,i) row
#define CJ 128           // j-rows per chunk (L / NCHUNK)
#define PSTRIDE 1280     // floats per partial row

#define SCALE_SCALAR 0.25f
#define SCALE_POINT  0.23570226039551584f   // (4.5*4)^-0.5
#define SCALE_TOTAL  0.5773502691896258f    // 3^-0.5

typedef __bf16 bf16_t;
typedef bf16_t bf16x8 __attribute__((ext_vector_type(8)));
typedef float  f32x4v __attribute__((ext_vector_type(4)));

// ---------------------------------------------------------------------------
// k_pack: x -> bf16 (row-major 1024x384), all six W -> WallT (672x384 bf16)
// ---------------------------------------------------------------------------
__global__ __launch_bounds__(256) void k_pack(
    const float* __restrict__ x,
    const float* __restrict__ Wq_s, const float* __restrict__ Wk_s, const float* __restrict__ Wv_s,
    const float* __restrict__ Wq_p, const float* __restrict__ Wk_p, const float* __restrict__ Wv_p,
    __hip_bfloat16* __restrict__ xb, __hip_bfloat16* __restrict__ WallT) {
    int idx = blockIdx.x * 256 + threadIdx.x;          // 651264 total
    const int T1 = 1024 * 384;
    if (idx < T1) {
        xb[idx] = __float2bfloat16(x[idx]);
    } else {
        int j = idx - T1;                              // 0 .. 258047
        int n = j / 384, k = j % 384;
        float v;
        if      (n < 128) v = Wq_s[k * 128 + n];
        else if (n < 256) v = Wk_s[k * 128 + (n - 128)];
        else if (n < 384) v = Wv_s[k * 128 + (n - 256)];
        else if (n < 480) v = Wq_p[k * 96  + (n - 384)];
        else if (n < 576) v = Wk_p[k * 96  + (n - 480)];
        else              v = Wv_p[k * 96  + (n - 576)];
        WallT[(size_t)n * 384 + k] = __float2bfloat16(v);
    }
}

// ---------------------------------------------------------------------------
// k_prep: Wout (1280,384) fp32 -> WoutT (384,1280) bf16, tiled LDS transpose
// ---------------------------------------------------------------------------
__global__ __launch_bounds__(256) void k_prep(const float* __restrict__ Wout,
                                              __hip_bfloat16* __restrict__ WoutT) {
    __shared__ float tile[64][65];
    const int tid = threadIdx.x;
    const int k0 = blockIdx.x * 64;   // 20 blocks
    const int n0 = blockIdx.y * 64;   // 6 blocks
#pragma unroll
    for (int s = 0; s < 16; ++s) {
        int idx = s * 256 + tid, kk = idx >> 6, nn = idx & 63;
        tile[kk][nn] = Wout[(size_t)(k0 + kk) * 384 + n0 + nn];
    }
    __syncthreads();
#pragma unroll
    for (int s = 0; s < 16; ++s) {
        int idx = s * 256 + tid, nn = idx >> 6, kk = idx & 63;
        WoutT[(size_t)(n0 + nn) * 1280 + k0 + kk] = __float2bfloat16(tile[kk][nn]);
    }
}

// ---------------------------------------------------------------------------
// k_projm: [1024,672] = xb[1024,384] @ Wall[384,672]  (bf16 MFMA, fp32 out)
// ---------------------------------------------------------------------------
__global__ __launch_bounds__(256) void k_projm(
    const __hip_bfloat16* __restrict__ xb, const __hip_bfloat16* __restrict__ WallT,
    float* __restrict__ q_s, float* __restrict__ k_s, float* __restrict__ v_s,
    float* __restrict__ praw) {
    __shared__ __align__(16) bf16_t As[64 * 40];
    __shared__ __align__(16) bf16_t Bs[48 * 40];
    const int tid = threadIdx.x;
    const int row0 = blockIdx.x * 64, col0 = blockIdx.y * 48;
    const int w = tid >> 6, lane = tid & 63;
    f32x4v acc[3] = {};

    for (int k0 = 0; k0 < 384; k0 += 32) {
        __syncthreads();
        {
            int rr = tid >> 2, q = tid & 3;
            *reinterpret_cast<int4*>(&As[rr * 40 + q * 8]) =
                *reinterpret_cast<const int4*>(&xb[(size_t)(row0 + rr) * 384 + k0 + q * 8]);
            if (tid < 192)
                *reinterpret_cast<int4*>(&Bs[rr * 40 + q * 8]) =
                    *reinterpret_cast<const int4*>(&WallT[(size_t)(col0 + rr) * 384 + k0 + q * 8]);
        }
        __syncthreads();
        const int m = lane & 15, kq = lane >> 4;
        bf16x8 af = *reinterpret_cast<const bf16x8*>(&As[(w * 16 + m) * 40 + kq * 8]);
#pragma unroll
        for (int c = 0; c < 3; ++c) {
            bf16x8 bfr = *reinterpret_cast<const bf16x8*>(&Bs[(c * 16 + m) * 40 + kq * 8]);
            acc[c] = __builtin_amdgcn_mfma_f32_16x16x32_bf16(af, bfr, acc[c], 0, 0, 0);
        }
    }
    const int colL = lane & 15, rbase = (lane >> 4) * 4;
#pragma unroll
    for (int c = 0; c < 3; ++c) {
        int col = col0 + c * 16 + colL;
#pragma unroll
        for (int rg = 0; rg < 4; ++rg) {
            int row = row0 + w * 16 + rbase + rg;
            float v = acc[c][rg];
            int bb = row >> 9, ll = row & 511;
            if (col < 384) {
                int kind = col >> 7, n = (col >> 4) & 7, d = col & 15;
                float* dst = (kind == 0) ? q_s : (kind == 1) ? k_s : v_s;
                dst[((size_t)(bb * NH + n) * L + ll) * DS + d] = v;
            } else {
                praw[(size_t)row * 288 + (col - 384)] = v;
            }
        }
    }
}

// ---------------------------------------------------------------------------
// k_euclid: praw (1024x288) -> q_p/k_p/v_p with forward euclid  x@r + t
// ---------------------------------------------------------------------------
__global__ __launch_bounds__(256) void k_euclid(
    const float* __restrict__ praw, const float* __restrict__ r, const float* __restrict__ t,
    float* __restrict__ q_p, float* __restrict__ k_p, float* __restrict__ v_p) {
    int idx = blockIdx.x * 256 + threadIdx.x;          // 294912 total
    int row = idx / 288, o = idx % 288;
    int arr = o / 96, oo = o % 96;
    int n = oo / 12, pc = oo % 12, p = pc / 3, c = pc % 3;
    const float* base = praw + (size_t)row * 288 + arr * 96 + n * 12 + p * 3;
    float acc = t[row * 3 + c];
#pragma unroll
    for (int k = 0; k < 3; ++k) acc += base[k] * r[row * 9 + k * 3 + c];
    float* dst = (arr == 0) ? q_p : (arr == 1) ? k_p : v_p;
    int bb = row >> 9, ll = row & 511;
    dst[((size_t)(bb * NH + n) * L + ll) * 12 + pc] = acc;
}

// ---------------------------------------------------------------------------
// k_attn v3 (resubmit — round-2 bench was an infra failure, no artifacts):
//  - phase A remap (wave=tid>>6, head=(tid>>3)&7, j=wave*8+(tid&7)): the 8
//    head-threads of a j-row are in ONE wave at the SAME LDS address ->
//    hardware broadcast. 8 distinct float4/instr (128B) instead of 32 (512B).
//    Rows padded to 33 float4 -> the 8 distinct rows hit 8 distinct bank
//    quads ((j+g) mod 8). No xor swizzle needed anywhere.
//  - phase C keeps e in REGISTERS (the staging thread's own 4 float4s) ->
//    zero LDS e-reads; p reads are 2-distinct broadcasts; ptT eliminated.
// Numerics: fp32 reassociation only (f32x4 accumulators).
// ---------------------------------------------------------------------------
__global__ __launch_bounds__(256) void k_attn(
    const float* __restrict__ e, const float* __restrict__ Wpb, const float* __restrict__ gamma,
    const float* __restrict__ q_s, const float* __restrict__ k_s, const float* __restrict__ v_s,
    const float* __restrict__ q_p, const float* __restrict__ k_p, const float* __restrict__ v_p,
    float* __restrict__ part) {
    __shared__ __align__(16) float et[TJ * 132];     // 32 rows x 33 float4, 16.9 KB
    __shared__ __align__(16) float wpbT[NH * 132];   // [n][k], row stride 132 floats
    __shared__ __align__(16) float pt[NH][36];       // [n][j] (+pad)
    __shared__ __align__(16) float qsl[NH * 16];
    __shared__ __align__(16) float qpl[NH * 12];
    __shared__ float gsh[NH];
    __shared__ float lred[32];                       // [wave][head] lsum partials

    const int tid = threadIdx.x;
    const int blk = blockIdx.x;
    const int bi = blk >> 2, chunk = blk & 3;
    const int b = bi >> 9, i = bi & 511, b8 = b * NH;

    // phase A/B mapping: broadcast-friendly
    const int wA = tid >> 6, nA = (tid >> 3) & 7, jrA = tid & 7;
    const int jA = wA * 8 + jrA;                    // local j in tile, 0..31
    // stage / phase C mapping
    const int jr2 = tid >> 5, g = tid & 31;

    // ---- prologue loads ----
    for (int idx = tid; idx < NH * DP; idx += 256) {
        int n = idx >> 7, k = idx & 127;
        wpbT[n * 132 + k] = Wpb[k * NH + n];
    }
    if (tid < 128) {
        int n = tid >> 4, d = tid & 15;
        qsl[n * 16 + d] = q_s[((size_t)(b8 + n) * L + i) * DS + d];
    } else if (tid < 224) {
        int o = tid - 128, n = o / 12, pc = o % 12;
        qpl[n * 12 + pc] = q_p[((size_t)(b8 + n) * L + i) * 12 + pc];
    } else if (tid < 232) {
        gsh[tid - 224] = gamma[tid - 224];
    }

    // sv ownership (out_scalar / out_point)
    const int nS = tid >> 4, dS = tid & 15;                      // tid < 128
    const int oP = tid - 128;
    const int nP = (oP >= 0 && oP < 96) ? oP / 12 : 0;
    const int pcP = (oP >= 0 && oP < 96) ? oP % 12 : 0;
    const float* vsp = v_s + (((size_t)(b8 + nS) * L + chunk * CJ) << 4) + dS;
    const float* vpp = v_p + ((size_t)(b8 + nP) * L + chunk * CJ) * 12 + pcP;

    const f32x4v* esrc4 = reinterpret_cast<const f32x4v*>(
        e + ((size_t)(b * L + i) * L + chunk * CJ) * DP);
    f32x4v* et4 = reinterpret_cast<f32x4v*>(et);

    float lsum = 0.f;
    f32x4v accPair[NH] = {};
    float accS = 0.f, accP = 0.f;
    f32x4v ev[4];   // register-held e slice: rows jr2+8s, cols 4g..4g+3

    for (int tile = 0; tile < CJ / TJ; ++tile) {
        const int j0 = tile * TJ;
        __syncthreads();                 // et & pt fully consumed; init visible
        // --- stage 32 rows of e (coalesced), keeping a register copy ---
#pragma unroll
        for (int s = 0; s < 4; ++s) {
            int j = jr2 + 8 * s;
            f32x4v v = esrc4[(size_t)(j0 + j) * 32 + g];
            et4[j * 33 + g] = v;
            ev[s] = v;
        }
        __syncthreads();
        // --- phase A: logit for (head nA, row jA) — broadcast e/wpb reads ---
        {
            const f32x4v* erow = et4 + jA * 33;
            const f32x4v* wrow = reinterpret_cast<const f32x4v*>(wpbT) + nA * 33;
            f32x4v b4 = {};
#pragma unroll 8
            for (int gg = 0; gg < 32; ++gg) b4 += erow[gg] * wrow[gg];
            float bsum = b4[0] + b4[1] + b4[2] + b4[3];

            const int jg = chunk * CJ + j0 + jA;
            const f32x4v* ksr = reinterpret_cast<const f32x4v*>(k_s + (((size_t)(b8 + nA) * L + jg) << 4));
            const f32x4v* q4 = reinterpret_cast<const f32x4v*>(&qsl[nA * 16]);
            f32x4v s4 = {};
#pragma unroll
            for (int gg = 0; gg < 4; ++gg) s4 += ksr[gg] * q4[gg];
            float ssum = s4[0] + s4[1] + s4[2] + s4[3];

            const f32x4v* kpr = reinterpret_cast<const f32x4v*>(k_p + ((size_t)(b8 + nA) * L + jg) * 12);
            const f32x4v* qp4 = reinterpret_cast<const f32x4v*>(&qpl[nA * 12]);
            f32x4v d4 = {};
#pragma unroll
            for (int gg = 0; gg < 3; ++gg) {
                f32x4v df = qp4[gg] - kpr[gg];
                d4 += df * df;
            }
            float sq = d4[0] + d4[1] + d4[2] + d4[3];

            float lg = SCALE_TOTAL * (ssum * SCALE_SCALAR + bsum
                                      - 0.5f * SCALE_POINT * gsh[nA] * sq);
            float pv = __expf(lg);
            lsum += pv;
            pt[nA][jA] = pv;
        }
        __syncthreads();                 // pt visible
        // --- phase C: out_pair from register e; p reads are broadcasts ---
        {
#pragma unroll
            for (int s = 0; s < 4; ++s) {
                int j = jr2 + 8 * s;
#pragma unroll
                for (int n = 0; n < NH; ++n)
                    accPair[n] += pt[n][j] * ev[s];
            }
        }
        // --- out_scalar / out_point ---
        if (tid < 128) {
            const float* vp = vsp + (size_t)j0 * 16;
#pragma unroll
            for (int q = 0; q < 8; ++q) {
                float4 p4 = *reinterpret_cast<const float4*>(&pt[nS][q * 4]);
                accS += p4.x * vp[(q * 4 + 0) * 16] + p4.y * vp[(q * 4 + 1) * 16]
                      + p4.z * vp[(q * 4 + 2) * 16] + p4.w * vp[(q * 4 + 3) * 16];
            }
        } else if (tid < 224) {
            const float* vp = vpp + (size_t)j0 * 12;
#pragma unroll
            for (int q = 0; q < 8; ++q) {
                float4 p4 = *reinterpret_cast<const float4*>(&pt[nP][q * 4]);
                accP += p4.x * vp[(q * 4 + 0) * 12] + p4.y * vp[(q * 4 + 1) * 12]
                      + p4.z * vp[(q * 4 + 2) * 12] + p4.w * vp[(q * 4 + 3) * 12];
            }
        }
    }

    // ---- write partials ----
    float* prow = part + (size_t)blk * PSTRIDE;
    // lsum: heads live on 8 consecutive lanes (nA*8+jrA) -> xor-reduce over jrA
    lsum += __shfl_xor(lsum, 1);  lsum += __shfl_xor(lsum, 2);  lsum += __shfl_xor(lsum, 4);
    if (jrA == 0) lred[wA * 8 + nA] = lsum;
    if (tid < 128) prow[1024 + tid] = accS;
    else if (tid < 224) prow[1152 + (tid - 128)] = accP;
    __syncthreads();
    if (tid < 8) prow[1248 + tid] = lred[tid] + lred[8 + tid] + lred[16 + tid] + lred[24 + tid];

    // pair reduction over 8 jr2 groups (log rounds through et scratch)
    f32x4v* red4 = reinterpret_cast<f32x4v*>(et);
    const int d4i = tid & 31, jsub = tid >> 5;
    if (jsub >= 4) {
#pragma unroll
        for (int n = 0; n < NH; ++n) red4[((jsub - 4) * NH + n) * 32 + d4i] = accPair[n];
    }
    __syncthreads();
    if (jsub < 4) {
#pragma unroll
        for (int n = 0; n < NH; ++n) accPair[n] += red4[(jsub * NH + n) * 32 + d4i];
    }
    __syncthreads();
    if (jsub == 2 || jsub == 3) {
#pragma unroll
        for (int n = 0; n < NH; ++n) red4[((jsub - 2) * NH + n) * 32 + d4i] = accPair[n];
    }
    __syncthreads();
    if (jsub < 2) {
#pragma unroll
        for (int n = 0; n < NH; ++n) accPair[n] += red4[(jsub * NH + n) * 32 + d4i];
    }
    __syncthreads();
    if (jsub == 1) {
#pragma unroll
        for (int n = 0; n < NH; ++n) red4[n * 32 + d4i] = accPair[n];
    }
    __syncthreads();
    if (jsub == 0) {
#pragma unroll
        for (int n = 0; n < NH; ++n) {
            accPair[n] += red4[n * 32 + d4i];
            *reinterpret_cast<f32x4v*>(&prow[n * 128 + d4i * 4]) = accPair[n];
        }
    }
}

// ---------------------------------------------------------------------------
// k_comb: combine 4 chunk-partials per (b,i); normalize; epilogue; write concat
// ---------------------------------------------------------------------------
__global__ __launch_bounds__(256) void k_comb(
    const float* __restrict__ part, const float* __restrict__ r, const float* __restrict__ t,
    __hip_bfloat16* __restrict__ concat) {
    __shared__ float comb[1256];
    __shared__ float rtsh[12], osh[96], o2sh[96];
    const int tid = threadIdx.x;
    const int bi = blockIdx.x;
    const float* base = part + (size_t)bi * NCHUNK * PSTRIDE;
#pragma unroll
    for (int s = 0; s < 5; ++s) {
        int idx = tid + s * 256;
        if (idx < 1256)
            comb[idx] = base[idx] + base[PSTRIDE + idx] + base[2 * PSTRIDE + idx] + base[3 * PSTRIDE + idx];
    }
    if (tid >= 244 && tid < 256) {
        int c = tid - 244;
        rtsh[c] = (c < 9) ? r[bi * 9 + c] : t[bi * 3 + (c - 9)];
    }
    __syncthreads();
    __hip_bfloat16* crow = concat + (size_t)bi * DCAT;
    if (tid < 128) crow[tid] = __float2bfloat16(comb[1024 + tid] / comb[1248 + (tid >> 4)]);
    for (int idx = tid; idx < 1024; idx += 256)
        crow[128 + idx] = __float2bfloat16(comb[idx] / comb[1248 + (idx >> 7)]);
    if (tid >= 128 && tid < 224) {
        int o = tid - 128;
        osh[o] = comb[1152 + o] / comb[1248 + o / 12];
    }
    __syncthreads();
    if (tid < 96) {   // inverse euclid: o_c = sum_k (op_k - t_k) * r[c][k]
        int n = tid / 12, pc = tid % 12, p = pc / 3, c = pc % 3;
        float oc = 0.f;
#pragma unroll
        for (int k = 0; k < 3; ++k)
            oc += (osh[n * 12 + p * 3 + k] - rtsh[9 + k]) * rtsh[c * 3 + k];
        crow[1152 + tid] = __float2bfloat16(oc);
        o2sh[tid] = oc;
    }
    __syncthreads();
    if (tid < 32) {
        int n = tid >> 2, p = tid & 3;
        float vx = o2sh[n * 12 + p * 3], vy = o2sh[n * 12 + p * 3 + 1], vz = o2sh[n * 12 + p * 3 + 2];
        crow[1248 + tid] = __float2bfloat16(sqrtf(vx * vx + vy * vy + vz * vz));
    }
}

// ---------------------------------------------------------------------------
// k_out: bf16 MFMA GEMM: out[1024,384] = concat[1024,1280] @ Wout + bout
// ---------------------------------------------------------------------------
__global__ __launch_bounds__(256) void k_out(const __hip_bfloat16* __restrict__ A,
                                             const __hip_bfloat16* __restrict__ Bt,
                                             const float* __restrict__ bout,
                                             float* __restrict__ out) {
    __shared__ __align__(16) bf16_t At[64 * 40];
    __shared__ __align__(16) bf16_t Bs[64 * 40];
    const int tid = threadIdx.x;
    const int row0 = blockIdx.x * 64, col0 = blockIdx.y * 64;
    const int wv = tid >> 6, lane = tid & 63;
    f32x4v acc[4] = {};

    for (int k0 = 0; k0 < 1280; k0 += 32) {
        __syncthreads();
        {
            int rr = tid >> 2, q = tid & 3;
            *reinterpret_cast<int4*>(&At[rr * 40 + q * 8]) =
                *reinterpret_cast<const int4*>(&A[(size_t)(row0 + rr) * 1280 + k0 + q * 8]);
            *reinterpret_cast<int4*>(&Bs[rr * 40 + q * 8]) =
                *reinterpret_cast<const int4*>(&Bt[(size_t)(col0 + rr) * 1280 + k0 + q * 8]);
        }
        __syncthreads();
        const int m = lane & 15, kq = lane >> 4;
        bf16x8 af = *reinterpret_cast<const bf16x8*>(&At[(wv * 16 + m) * 40 + kq * 8]);
#pragma unroll
        for (int nt = 0; nt < 4; ++nt) {
            bf16x8 bfr = *reinterpret_cast<const bf16x8*>(&Bs[(nt * 16 + m) * 40 + kq * 8]);
            acc[nt] = __builtin_amdgcn_mfma_f32_16x16x32_bf16(af, bfr, acc[nt], 0, 0, 0);
        }
    }
    const int col_l = lane & 15, rbase = (lane >> 4) * 4;
#pragma unroll
    for (int nt = 0; nt < 4; ++nt) {
        int col = col0 + nt * 16 + col_l;
        float bo = bout[col];
#pragma unroll
        for (int rg = 0; rg < 4; ++rg) {
            int rowg = row0 + wv * 16 + rbase + rg;
            out[(size_t)rowg * 384 + col] = acc[nt][rg] + bo;
        }
    }
}

// ---------------------------------------------------------------------------
extern "C" void kernel_launch(void* const* d_in, const int* in_sizes, int n_in,
                              void* d_out, int out_size, void* d_ws, size_t ws_size,
                              hipStream_t stream) {
    const float* x     = (const float*)d_in[0];
    const float* e     = (const float*)d_in[1];
    const float* r     = (const float*)d_in[2];
    const float* t     = (const float*)d_in[3];
    const float* Wq_s  = (const float*)d_in[4];
    const float* Wk_s  = (const float*)d_in[5];
    const float* Wv_s  = (const float*)d_in[6];
    const float* Wpb   = (const float*)d_in[7];
    const float* Wq_p  = (const float*)d_in[8];
    const float* Wk_p  = (const float*)d_in[9];
    const float* Wv_p  = (const float*)d_in[10];
    const float* gamma = (const float*)d_in[11];
    const float* Wout  = (const float*)d_in[12];
    const float* bout  = (const float*)d_in[13];

    float* ws   = (float*)d_ws;
    float* q_s  = ws + 0;          // 131072
    float* k_s  = ws + 131072;     // 131072
    float* v_s  = ws + 262144;     // 131072
    float* q_p  = ws + 393216;     // 98304
    float* k_p  = ws + 491520;     // 98304
    float* v_p  = ws + 589824;     // 98304
    float* praw = ws + 688128;     // 294912
    __hip_bfloat16* xb     = (__hip_bfloat16*)((char*)d_ws + 3932160); // 393216 bf16
    __hip_bfloat16* WallT  = (__hip_bfloat16*)((char*)d_ws + 4718592); // 258048 bf16
    __hip_bfloat16* concat = (__hip_bfloat16*)((char*)d_ws + 5234688); // 1310720 bf16
    __hip_bfloat16* WoutT  = (__hip_bfloat16*)((char*)d_ws + 7856128); // 491520 bf16
    float* part = (float*)((char*)d_ws + 8847360);                     // 4096*1280 fp32
    float* out = (float*)d_out;

    hipLaunchKernelGGL(k_pack, dim3(2544), dim3(256), 0, stream,
                       x, Wq_s, Wk_s, Wv_s, Wq_p, Wk_p, Wv_p, xb, WallT);
    hipLaunchKernelGGL(k_prep, dim3(20, 6), dim3(256), 0, stream, Wout, WoutT);
    hipLaunchKernelGGL(k_projm, dim3(16, 14), dim3(256), 0, stream,
                       xb, WallT, q_s, k_s, v_s, praw);
    hipLaunchKernelGGL(k_euclid, dim3(1152), dim3(256), 0, stream,
                       praw, r, t, q_p, k_p, v_p);
    hipLaunchKernelGGL(k_attn, dim3(4096), dim3(256), 0, stream,
                       e, Wpb, gamma, q_s, k_s, v_s, q_p, k_p, v_p, part);
    hipLaunchKernelGGL(k_comb, dim3(1024), dim3(256), 0, stream,
                       part, r, t, concat);
    hipLaunchKernelGGL(k_out, dim3(16, 6), dim3(256), 0, stream, concat, WoutT, bout, out);
}